// Round 8
// baseline (355.749 us; speedup 1.0000x reference)
//
#include <hip/hip_runtime.h>
#include <hip/hip_bf16.h>
#include <hip/hip_fp16.h>

// PPGNN: lift -> 5x (mean-aggregate + Lotka-Volterra Euler step) -> readout
// N=50000, E=800000, C_IN=128, H=96, C_OUT=40, L=5, DT=0.05
//
// Master state S: fp16, row = 192 halfs = 96 uints, updated IN-PLACE by the
// layer kernels. fp8 e4m3 mirror F in THREE CHANNEL PLANES of 64-B rows
// (plane p = h in [32p,32p+32), row = 16 dwords, +1 sentinel zero row per
// plane); double-buffered across layers.
//
// Layer: ONE kernel per layer covers all 3 planes with 64-node tiles
// (782 blocks/layer, not 3x1563): the csr index span is LDS-staged ONCE
// and reused by 3 planes x 2 node-slots, and per-edge offsets are shared
// across the 3 plane bases. This amortizes the per-block prologue chain
// (rowinfo load -> csr stage -> sync) 6x vs the plane-split version.
// 8 lanes per row (uint2/lane); lists padded per node to a multiple of 8
// with sentinel N (zero row): no tail, no masking.
//
// CSR build: fixed-capacity buckets (128 nodes/bucket, cap 3072 vs mean
// 2048, sigma ~45), TWO kernels (scatter, then per-bucket CSR). NOTE:
// in-kernel grid-barrier fusions measured 10x worse (R3: 506 MB refetch;
// R5: 135 us build) -- device-scope spin barriers serialize this chip;
// do not re-fuse.

#define HDIM 96
#define CIN 128
#define COUT 40
#define NLAYER 5
#define DTC 0.05f

#define BK_SHIFT 7
#define BK_SIZE 128
#define EPB 2048      // edges per block in bucket scatter
#define BCAP 3072     // fixed bucket capacity (mean 2048, >20 sigma margin)
#define BSTRIDE 4096  // csr region per bucket: BCAP + 1024 slack (mult-8 pad)

typedef float  vfloat2 __attribute__((ext_vector_type(2)));
typedef float  vfloat4 __attribute__((ext_vector_type(4)));
typedef short  vshort8 __attribute__((ext_vector_type(8)));

__device__ __forceinline__ unsigned bf16_rne(float f) {
    unsigned u = __float_as_uint(f);
    return (u + 0x7fffu + ((u >> 16) & 1u)) >> 16;
}

__device__ __forceinline__ unsigned pack_bf16_pair(float xf, float yf) {
    return bf16_rne(xf) | (bf16_rne(yf) << 16);
}

__device__ __forceinline__ unsigned pack_f16_pair(float a, float b) {
    unsigned ha = (unsigned)__half_as_ushort(__float2half_rn(a));
    unsigned hb = (unsigned)__half_as_ushort(__float2half_rn(b));
    return ha | (hb << 16);
}

__device__ __forceinline__ float f16_lo(unsigned u) {
    return __half2float(__ushort_as_half((unsigned short)(u & 0xffffu)));
}
__device__ __forceinline__ float f16_hi(unsigned u) {
    return __half2float(__ushort_as_half((unsigned short)(u >> 16)));
}

__device__ __forceinline__ unsigned pack_fp8_quad(float x0, float y0, float x1, float y1) {
    int lo = __builtin_amdgcn_cvt_pk_fp8_f32(x0, y0, 0, false);
    int full = __builtin_amdgcn_cvt_pk_fp8_f32(x1, y1, lo, true);
    return (unsigned)full;
}

// tanh via hw exp/rcp: 1 - 2/(e^{2x}+1). ~1e-7 err.
__device__ __forceinline__ float fast_tanh(float x) {
    float e = __expf(2.0f * x);
    return 1.0f - 2.0f * __builtin_amdgcn_rcpf(e + 1.0f);
}

// ---------------- Weight prep + cursor zero + sentinel zeroing ----------------

__global__ __launch_bounds__(256) void wprep_kernel(
    const float* __restrict__ Wx, const float* __restrict__ bx,
    const float* __restrict__ Wy, const float* __restrict__ by,
    unsigned short* __restrict__ WcT, float* __restrict__ bc,
    int* __restrict__ gcur, int NB,
    unsigned* __restrict__ F0, unsigned* __restrict__ F1, int N) {
    int t = blockIdx.x * blockDim.x + threadIdx.x;
    if (t < NB) gcur[t] = 0;
    if (t < 192 * 128) {
        int cc = t >> 7;
        int k = t & 127;
        int h = cc >> 1;
        float w = (cc & 1) ? Wy[k * HDIM + h] : Wx[k * HDIM + h];
        WcT[cc * 128 + k] = (unsigned short)bf16_rne(w);
    }
    if (t < 192) {
        int h = t >> 1;
        bc[t] = (t & 1) ? by[h] : bx[h];
    }
    if (blockIdx.x == 0 && threadIdx.x < 48) {
        // zero sentinel row N of each of the 3 planes, both F buffers
        int plane = threadIdx.x >> 4, d = threadIdx.x & 15;
        size_t o = ((size_t)plane * (N + 1) + N) * 16 + d;
        F0[o] = 0u;
        F1[o] = 0u;
    }
}

// ---------------- Bucket scatter (fixed-capacity, atomic-light) ----------------

__global__ __launch_bounds__(256) void bscatter_kernel(
    const int* __restrict__ src, const int* __restrict__ dst,
    int* __restrict__ gcur, unsigned* __restrict__ packed, int E, int NB) {
    __shared__ int h[512];
    __shared__ int cur[512];
    for (int i = threadIdx.x; i < NB; i += 256) h[i] = 0;
    __syncthreads();
    int base = blockIdx.x * EPB;
    int end = min(E, base + EPB);
    for (int e = base + threadIdx.x; e < end; e += 256)
        atomicAdd(&h[dst[e] >> BK_SHIFT], 1);
    __syncthreads();
    for (int i = threadIdx.x; i < NB; i += 256)
        cur[i] = h[i] ? atomicAdd(&gcur[i], h[i]) : 0;
    __syncthreads();
    for (int e = base + threadIdx.x; e < end; e += 256) {
        int d = dst[e];
        int b = d >> BK_SHIFT;
        int pos = atomicAdd(&cur[b], 1);
        if (pos < BCAP)  // never triggers at >20 sigma; guards OOB
            packed[(size_t)b * BCAP + pos] =
                (unsigned)src[e] | ((unsigned)(d & (BK_SIZE - 1)) << 17);
    }
}

// ---------------- Per-bucket CSR, per-node padding to multiple of 8 ----------------
// rowinfo[node] = { csr_begin (21b) | padded_count/4 << 21, bits(deg_inv) }
// csr entries are ushort node indices (sentinel = N). begin is a multiple
// of 8 -> every 8-index batch is one 16B-aligned uint4.

__global__ __launch_bounds__(256) void bcsr_kernel(
    const unsigned* __restrict__ packed, const int* __restrict__ gcur,
    uint2* __restrict__ rowinfo, unsigned short* __restrict__ csr, int N, int NB) {
    __shared__ int ldeg[BK_SIZE];
    __shared__ int sscan[BK_SIZE];
    __shared__ int lcur[BK_SIZE];
    int b = blockIdx.x;
    int t = threadIdx.x;
    int cnt = min(gcur[b], BCAP);
    const unsigned* pk = packed + (size_t)b * BCAP;
    int wbase = b * BSTRIDE;
    if (t < BK_SIZE) ldeg[t] = 0;
    __syncthreads();
    for (int e = t; e < cnt; e += 256)
        atomicAdd(&ldeg[(pk[e] >> 17) & (BK_SIZE - 1)], 1);
    __syncthreads();
    int deg = 0, pad = 0;
    if (t < BK_SIZE) {
        deg = ldeg[t];
        pad = (deg + 7) & ~7;
        sscan[t] = pad;
    }
    __syncthreads();
    for (int off = 1; off < BK_SIZE; off <<= 1) {
        int tv = (t < BK_SIZE && t >= off) ? sscan[t - off] : 0;
        __syncthreads();
        if (t < BK_SIZE) sscan[t] += tv;
        __syncthreads();
    }
    int gpos = 0;
    if (t < BK_SIZE) {
        gpos = wbase + sscan[t] - pad;  // exclusive padded offset
        lcur[t] = gpos;
        int node = b * BK_SIZE + t;
        if (node < N) {
            rowinfo[node] = make_uint2(
                (unsigned)gpos | ((unsigned)(pad >> 2) << 21),
                __float_as_uint(1.0f / fmaxf((float)deg, 1.0f)));
        }
    }
    __syncthreads();
    for (int e = t; e < cnt; e += 256) {
        unsigned p = pk[e];
        int l = (p >> 17) & (BK_SIZE - 1);
        int pos = atomicAdd(&lcur[l], 1);
        csr[pos] = (unsigned short)(p & 0x1FFFFu);
    }
    __syncthreads();
    if (t < BK_SIZE) {
        // fill pad slots with sentinel N (zero row)
        for (int p = lcur[t]; p < gpos + pad; p++) csr[p] = (unsigned short)N;
    }
}

// ---------------- Lift (MFMA): tanh(x @ [Wx|Wy] + b) ----------------

#define LW_STRIDE 136
#define TILE_STRIDE 200  // ushorts: 400 B rows, 16B-aligned

__global__ __launch_bounds__(256) void lift_mfma_kernel(
    const float* __restrict__ x, const unsigned short* __restrict__ WcT,
    const float* __restrict__ bc, unsigned* __restrict__ S,
    unsigned* __restrict__ F, int N) {
    __shared__ __align__(16) char smem[192 * LW_STRIDE * 2];  // 52224 B
    __shared__ float sBc[192];
    unsigned short* sW = (unsigned short*)smem;
    unsigned short* tile = (unsigned short*)smem;  // reused after barrier
    int t = threadIdx.x;

    {
        const unsigned* g = (const unsigned*)WcT;  // 192*64 uints
        unsigned* s = (unsigned*)sW;
        for (int i = t; i < 192 * 64; i += 256) {
            int cc = i >> 6;
            int kp = i & 63;
            s[cc * (LW_STRIDE / 2) + kp] = g[i];
        }
    }
    if (t < 192) sBc[t] = bc[t];
    __syncthreads();

    int wv = t >> 6;
    int lane = t & 63;
    int quad = lane >> 4;
    int m = lane & 15;
    int mbase = blockIdx.x * 64 + wv * 16;

    int anode = mbase + m;
    if (anode >= N) anode = N - 1;  // clamp; stores guarded
    const float* xrow = x + (size_t)anode * CIN;

    vfloat4 acc[12];
#pragma unroll
    for (int i = 0; i < 12; i++) acc[i] = (vfloat4){0.f, 0.f, 0.f, 0.f};

#pragma unroll
    for (int kt = 0; kt < 4; kt++) {
        int k0 = kt * 32 + quad * 8;
        float4 xa = *(const float4*)(xrow + k0);
        float4 xb = *(const float4*)(xrow + k0 + 4);
        uint4 ua;
        ua.x = pack_bf16_pair(xa.x, xa.y);
        ua.y = pack_bf16_pair(xa.z, xa.w);
        ua.z = pack_bf16_pair(xb.x, xb.y);
        ua.w = pack_bf16_pair(xb.z, xb.w);
        vshort8 a = *(vshort8*)&ua;
#pragma unroll
        for (int nt = 0; nt < 12; nt++) {
            vshort8 b = *(const vshort8*)&sW[(nt * 16 + m) * LW_STRIDE + k0];
            acc[nt] = __builtin_amdgcn_mfma_f32_16x16x32_bf16(a, b, acc[nt], 0, 0, 0);
        }
    }

    // ---- epilogue phase 1: tanh + fp16 into LDS tile ----
    __syncthreads();  // all waves done reading sW
#pragma unroll
    for (int nt = 0; nt < 12; nt++) {
        int ccb = nt * 16 + m;
        float bco = sBc[ccb];
#pragma unroll
        for (int r = 0; r < 4; r++) {
            int nl = wv * 16 + quad * 4 + r;  // local node 0..63
            float v = fast_tanh(acc[nt][r] + bco);
            tile[nl * TILE_STRIDE + ccb] = __half_as_ushort(__float2half_rn(v));
        }
    }
    __syncthreads();

    // ---- epilogue phase 2: coalesced S (uint4) + plane-F (uint2) stores ----
    int nbase = blockIdx.x * 64;
#pragma unroll
    for (int i = 0; i < 6; i++) {
        int idx = i * 256 + t;       // 0..1535
        int nl = idx / 24;           // local node (24 uint4 per 96-dword row)
        int pos = idx - nl * 24;
        int node = nbase + nl;
        uint4 u = *(const uint4*)&tile[nl * TILE_STRIDE + pos * 8];
        if (node < N) {
            *(uint4*)(S + (size_t)node * 96 + pos * 4) = u;
            float f0 = f16_lo(u.x), f1 = f16_hi(u.x);
            float f2 = f16_lo(u.y), f3 = f16_hi(u.y);
            float f4 = f16_lo(u.z), f5 = f16_hi(u.z);
            float f6 = f16_lo(u.w), f7 = f16_hi(u.w);
            uint2 fq = make_uint2(pack_fp8_quad(f0, f1, f2, f3),
                                  pack_fp8_quad(f4, f5, f6, f7));
            // global F dword pair (2pos, 2pos+1) -> plane = pos/8, slot = 2pos mod 16
            int plane = pos >> 3;
            int slot = (2 * pos) & 15;
            *(uint2*)(F + ((size_t)plane * (N + 1) + node) * 16 + slot) = fq;
        }
    }
}

// ---------------- Layer pass: mean agg + LV Euler update (all 3 planes) ----------------
// 64-node tile per block (4 waves; 8-lane group owns a node, 2 node-slots
// sequential). csr span staged in LDS once, reused by both slots and all
// planes. Per edge: one shared offset, 3 uint2 gathers (one per plane),
// 12 channels unpacked into 12 vfloat2 accumulators. Epilogue: 3 in-place
// S uint4 RMWs + 3 Fn uint2 stores per node. Accumulation order per
// channel matches the reference (csr order).

#define SPAN_CAP 8192  // ushorts (16 KB LDS); fallback to global if exceeded

__global__ __launch_bounds__(256) void layer_kernel(
    const unsigned* __restrict__ F, unsigned* __restrict__ S,
    unsigned* __restrict__ Fn,
    const uint2* __restrict__ rowinfo, const unsigned short* __restrict__ csr,
    const float* __restrict__ alpha, const float* __restrict__ beta,
    const float* __restrict__ gamma, const float* __restrict__ delta,
    int N) {
    __shared__ __align__(16) unsigned short sidx[SPAN_CAP];
    unsigned pstride = (unsigned)(N + 1) * 16u;
    const unsigned* F0 = F;
    const unsigned* F1 = F + pstride;
    const unsigned* F2 = F + 2 * (size_t)pstride;

    int t = threadIdx.x;
    int wave = t >> 6;
    int lane = t & 63;
    int li = lane & 7;
    int g = lane >> 3;
    unsigned tli = (unsigned)(2 * li);

    // ---- stage the tile's csr span in LDS (once; reused 6x) ----
    int n0 = blockIdx.x * 64;
    int nlast = min(n0 + 63, N - 1);
    unsigned ri0x = rowinfo[n0].x;
    unsigned riLx = rowinfo[nlast].x;
    unsigned beg0 = ri0x & 0x1FFFFFu;
    unsigned endL = (riLx & 0x1FFFFFu) + ((riLx >> 21) << 2);
    int span = (int)(endL - beg0);     // multiple of 8
    bool use_lds = (span <= SPAN_CAP);
    if (use_lds) {
        const uint4* gs = (const uint4*)(csr + beg0);
        uint4* ld = (uint4*)sidx;
        for (int i = t; i < (span >> 3); i += 256) ld[i] = gs[i];
    }
    __syncthreads();

#define UNP(u, A0, A1, A2, A3)                                              \
    do {                                                                    \
        A0 += __builtin_amdgcn_cvt_pk_f32_fp8((int)(u).x, false);           \
        A1 += __builtin_amdgcn_cvt_pk_f32_fp8((int)(u).x, true);            \
        A2 += __builtin_amdgcn_cvt_pk_f32_fp8((int)(u).y, false);           \
        A3 += __builtin_amdgcn_cvt_pk_f32_fp8((int)(u).y, true);            \
    } while (0)

#define GATHER4(i0, i1, i2, i3)                                             \
    do {                                                                    \
        unsigned o0 = ((i0) << 4) + tli;                                    \
        unsigned o1 = ((i1) << 4) + tli;                                    \
        unsigned o2 = ((i2) << 4) + tli;                                    \
        unsigned o3 = ((i3) << 4) + tli;                                    \
        uint2 p00 = *(const uint2*)(F0 + o0);                               \
        uint2 p01 = *(const uint2*)(F0 + o1);                               \
        uint2 p02 = *(const uint2*)(F0 + o2);                               \
        uint2 p03 = *(const uint2*)(F0 + o3);                               \
        uint2 p10 = *(const uint2*)(F1 + o0);                               \
        uint2 p11 = *(const uint2*)(F1 + o1);                               \
        uint2 p12 = *(const uint2*)(F1 + o2);                               \
        uint2 p13 = *(const uint2*)(F1 + o3);                               \
        uint2 p20 = *(const uint2*)(F2 + o0);                               \
        uint2 p21 = *(const uint2*)(F2 + o1);                               \
        uint2 p22 = *(const uint2*)(F2 + o2);                               \
        uint2 p23 = *(const uint2*)(F2 + o3);                               \
        UNP(p00, a00, a01, a02, a03); UNP(p01, a00, a01, a02, a03);         \
        UNP(p02, a00, a01, a02, a03); UNP(p03, a00, a01, a02, a03);         \
        UNP(p10, a10, a11, a12, a13); UNP(p11, a10, a11, a12, a13);         \
        UNP(p12, a10, a11, a12, a13); UNP(p13, a10, a11, a12, a13);         \
        UNP(p20, a20, a21, a22, a23); UNP(p21, a20, a21, a22, a23);         \
        UNP(p22, a20, a21, a22, a23); UNP(p23, a20, a21, a22, a23);         \
    } while (0)

#pragma unroll 1
    for (int r = 0; r < 2; r++) {
        int node = n0 + wave * 16 + r * 8 + g;
        bool nvalid = node < N;
        int nclamp = nvalid ? node : N - 1;
        uint2 ri = rowinfo[nclamp];
        unsigned beg = ri.x & 0x1FFFFFu;
        int cnt = nvalid ? (int)((ri.x >> 21) << 2) : 0;  // padded, mult of 8
        float dinv = __uint_as_float(ri.y);

        vfloat2 a00 = {0.f, 0.f}, a01 = {0.f, 0.f}, a02 = {0.f, 0.f}, a03 = {0.f, 0.f};
        vfloat2 a10 = {0.f, 0.f}, a11 = {0.f, 0.f}, a12 = {0.f, 0.f}, a13 = {0.f, 0.f};
        vfloat2 a20 = {0.f, 0.f}, a21 = {0.f, 0.f}, a22 = {0.f, 0.f}, a23 = {0.f, 0.f};

        if (use_lds) {
            unsigned lbeg = beg - beg0;
            for (int j = 0; j < cnt; j += 8) {
                uint4 w = *(const uint4*)(sidx + lbeg + (unsigned)j);
                GATHER4(w.x & 0xffffu, w.x >> 16, w.y & 0xffffu, w.y >> 16);
                GATHER4(w.z & 0xffffu, w.z >> 16, w.w & 0xffffu, w.w >> 16);
            }
        } else {
            for (int j = 0; j < cnt; j += 8) {
                uint4 w = *(const uint4*)(csr + beg + (unsigned)j);
                GATHER4(w.x & 0xffffu, w.x >> 16, w.y & 0xffffu, w.y >> 16);
                GATHER4(w.z & 0xffffu, w.z >> 16, w.w & 0xffffu, w.w >> 16);
            }
        }

        if (!nvalid) continue;

#define UPD(P, A0, A1, A2, A3)                                              \
    do {                                                                    \
        int h0 = P * 32 + 4 * li;                                           \
        float4 av = *(const float4*)(alpha + h0);                           \
        float4 bv = *(const float4*)(beta + h0);                            \
        float4 gv = *(const float4*)(gamma + h0);                           \
        float4 dv = *(const float4*)(delta + h0);                           \
        unsigned* srow = S + (size_t)node * 96 + h0;                        \
        uint4 su = *(const uint4*)srow;                                     \
        float x0 = f16_lo(su.x), y0 = f16_hi(su.x);                         \
        float x1 = f16_lo(su.y), y1 = f16_hi(su.y);                         \
        float x2 = f16_lo(su.z), y2 = f16_hi(su.z);                         \
        float x3 = f16_lo(su.w), y3 = f16_hi(su.w);                         \
        float ox0 = x0 + DTC * x0 * (av.x - bv.x * (A0.y * dinv));          \
        float oy0 = y0 + DTC * y0 * (-gv.x + dv.x * (A0.x * dinv));         \
        float ox1 = x1 + DTC * x1 * (av.y - bv.y * (A1.y * dinv));          \
        float oy1 = y1 + DTC * y1 * (-gv.y + dv.y * (A1.x * dinv));         \
        float ox2 = x2 + DTC * x2 * (av.z - bv.z * (A2.y * dinv));          \
        float oy2 = y2 + DTC * y2 * (-gv.z + dv.z * (A2.x * dinv));         \
        float ox3 = x3 + DTC * x3 * (av.w - bv.w * (A3.y * dinv));          \
        float oy3 = y3 + DTC * y3 * (-gv.w + dv.w * (A3.x * dinv));         \
        uint4 so;                                                           \
        so.x = pack_f16_pair(ox0, oy0);                                     \
        so.y = pack_f16_pair(ox1, oy1);                                     \
        so.z = pack_f16_pair(ox2, oy2);                                     \
        so.w = pack_f16_pair(ox3, oy3);                                     \
        *(uint4*)srow = so;                                                 \
        if (Fn) {                                                           \
            uint2 fo;                                                       \
            fo.x = pack_fp8_quad(ox0, oy0, ox1, oy1);                       \
            fo.y = pack_fp8_quad(ox2, oy2, ox3, oy3);                       \
            *(uint2*)(Fn + (size_t)P * pstride + (unsigned)node * 16u + tli) = fo; \
        }                                                                   \
    } while (0)

        UPD(0, a00, a01, a02, a03);
        UPD(1, a10, a11, a12, a13);
        UPD(2, a20, a21, a22, a23);
#undef UPD
    }
#undef GATHER4
#undef UNP
}

// ---------------- Readout: out = [X,Y] @ Wr + br via f16 MFMA ----------------

#define WG_STRIDE 200

__global__ __launch_bounds__(256) void readout_mfma_kernel(
    const unsigned short* __restrict__ sh, const float* __restrict__ Wr,
    const float* __restrict__ br, float* __restrict__ out, int N) {
    __shared__ unsigned short sW[48 * WG_STRIDE];
    __shared__ float sB[48];
    int t = threadIdx.x;

    for (int i = t; i < 48 * 192; i += 256) {
        int n = i / 192;
        int kk = i - n * 192;
        int h = kk >> 1;
        float w = 0.f;
        if (n < COUT) w = (kk & 1) ? Wr[(HDIM + h) * COUT + n] : Wr[h * COUT + n];
        sW[n * WG_STRIDE + kk] = __half_as_ushort(__float2half_rn(w));
    }
    if (t < 48) sB[t] = (t < COUT) ? br[t] : 0.f;
    __syncthreads();

    int wv = t >> 6;
    int lane = t & 63;
    int quad = lane >> 4;
    int m = lane & 15;
    int mbase = blockIdx.x * 64 + wv * 16;

    int anode = mbase + m;
    if (anode >= N) anode = N - 1;
    const unsigned short* arow = sh + (size_t)anode * 192;

    vfloat4 acc0 = {0.f, 0.f, 0.f, 0.f};
    vfloat4 acc1 = {0.f, 0.f, 0.f, 0.f};
    vfloat4 acc2 = {0.f, 0.f, 0.f, 0.f};

#pragma unroll
    for (int kt = 0; kt < 6; kt++) {
        int k0 = kt * 32 + quad * 8;
        vshort8 a = *(const vshort8*)(arow + k0);
        vshort8 b0 = *(const vshort8*)&sW[(0 * 16 + m) * WG_STRIDE + k0];
        vshort8 b1 = *(const vshort8*)&sW[(1 * 16 + m) * WG_STRIDE + k0];
        vshort8 b2 = *(const vshort8*)&sW[(2 * 16 + m) * WG_STRIDE + k0];
        acc0 = __builtin_amdgcn_mfma_f32_16x16x32_f16(a, b0, acc0, 0, 0, 0);
        acc1 = __builtin_amdgcn_mfma_f32_16x16x32_f16(a, b1, acc1, 0, 0, 0);
        acc2 = __builtin_amdgcn_mfma_f32_16x16x32_f16(a, b2, acc2, 0, 0, 0);
    }

    float bo0 = sB[m];
    float bo1 = sB[16 + m];
    float bo2 = (m < 8) ? sB[32 + m] : 0.f;
#pragma unroll
    for (int r = 0; r < 4; r++) {
        int node = mbase + quad * 4 + r;
        if (node < N) {
            float* orow = out + (size_t)node * COUT;
            orow[m] = acc0[r] + bo0;
            orow[16 + m] = acc1[r] + bo1;
            if (m < 8) orow[32 + m] = acc2[r] + bo2;
        }
    }
}

// ---------------- launch ----------------

extern "C" void kernel_launch(void* const* d_in, const int* in_sizes, int n_in,
                              void* d_out, int out_size, void* d_ws, size_t ws_size,
                              hipStream_t stream) {
    const float* x     = (const float*)d_in[0];
    const int*   ei    = (const int*)d_in[1];
    const float* Wx    = (const float*)d_in[2];
    const float* bx    = (const float*)d_in[3];
    const float* Wy    = (const float*)d_in[4];
    const float* by    = (const float*)d_in[5];
    const float* alpha = (const float*)d_in[6];
    const float* beta  = (const float*)d_in[7];
    const float* gamma = (const float*)d_in[8];
    const float* delta = (const float*)d_in[9];
    const float* Wr    = (const float*)d_in[10];
    const float* br    = (const float*)d_in[11];

    const int N = in_sizes[0] / CIN;
    const int E = in_sizes[1] / 2;
    const int NB = (N + BK_SIZE - 1) >> BK_SHIFT;     // 391 for N=50000 (<=512)
    const int nchunk = (E + EPB - 1) / EPB;           // 391 for E=800000
    const int nblk64 = (N + 63) / 64;                 // 782 64-node tiles

    char* ws = (char*)d_ws;
    size_t off = 0;
    auto alloc = [&](size_t bytes) -> void* {
        off = (off + 255) & ~(size_t)255;
        void* p = ws + off;
        off += bytes;
        return p;
    };
    int* gcur          = (int*)alloc((size_t)NB * sizeof(int));
    unsigned* pckd     = (unsigned*)alloc((size_t)NB * BCAP * sizeof(unsigned));
    uint2* rowinfo     = (uint2*)alloc((size_t)N * sizeof(uint2));
    unsigned short* csr = (unsigned short*)alloc(((size_t)NB * BSTRIDE + 64) * sizeof(unsigned short));
    unsigned* Sa   = (unsigned*)alloc((size_t)N * 96 * sizeof(unsigned));        // fp16 state (in-place)
    unsigned* Fa   = (unsigned*)alloc((size_t)(N + 1) * 48 * sizeof(unsigned));  // 3 fp8 planes
    unsigned* Fb   = (unsigned*)alloc((size_t)(N + 1) * 48 * sizeof(unsigned));
    unsigned short* WcT = (unsigned short*)alloc((size_t)192 * 128 * sizeof(unsigned short));
    float* bc      = (float*)alloc((size_t)192 * sizeof(float));
    (void)ws_size;

    const int* e_src = ei;
    const int* e_dst = ei + E;

    // wprep first: zeroes bucket cursors + sentinel F rows, builds WcT/bc
    wprep_kernel<<<(192 * 128 + 255) / 256, 256, 0, stream>>>(
        Wx, bx, Wy, by, WcT, bc, gcur, NB, Fa, Fb, N);

    bscatter_kernel<<<nchunk, 256, 0, stream>>>(e_src, e_dst, gcur, pckd, E, NB);
    bcsr_kernel<<<NB, 256, 0, stream>>>(pckd, gcur, rowinfo, csr, N, NB);

    lift_mfma_kernel<<<(N + 63) / 64, 256, 0, stream>>>(x, WcT, bc, Sa, Fa, N);

    const unsigned* Fc = Fa;
    unsigned* Fnx = Fb;
    for (int l = 0; l < NLAYER; l++) {
        bool last = (l == NLAYER - 1);
        layer_kernel<<<nblk64, 256, 0, stream>>>(
            Fc, Sa, last ? (unsigned*)nullptr : Fnx,
            rowinfo, csr,
            alpha + l * HDIM, beta + l * HDIM, gamma + l * HDIM, delta + l * HDIM,
            N);
        const unsigned* tf = Fc; Fc = Fnx; Fnx = (unsigned*)tf;
    }

    readout_mfma_kernel<<<(N + 63) / 64, 256, 0, stream>>>(
        (const unsigned short*)Sa, Wr, br, (float*)d_out, N);
}

// Round 9
// 283.921 us; speedup vs baseline: 1.2530x; 1.2530x over previous
//
#include <hip/hip_runtime.h>
#include <hip/hip_bf16.h>
#include <hip/hip_fp16.h>

// PPGNN: lift -> 5x (mean-aggregate + Lotka-Volterra Euler step) -> readout
// N=50000, E=800000, C_IN=128, H=96, C_OUT=40, L=5, DT=0.05
//
// Master state S: fp16, row = 192 halfs = 96 uints, updated IN-PLACE by the
// layer kernels. fp8 e4m3 mirror F in THREE CHANNEL PLANES of 64-B rows
// (plane p = h in [32p,32p+32), row = 16 dwords, +1 sentinel zero row per
// plane); double-buffered across layers.
//
// Layer scheduling is XCD-PINNED: with blockIdx round-robin across the 8
// XCDs (bid & 7), each XCD executes a contiguous plane-major slice of the
// (plane, tile) task list, so each 3.2 MB plane is resident in only 3-4
// XCD L2s instead of all 8 -- cutting the gather-side L2-fill traffic
// (measured 105 MB/layer when unpinned+merged) by ~2.5x. Pure scheduling:
// accumulation order is unchanged.
//
// Layer gather: 8 lanes per row (uint2/lane), 8 nodes per wave; csr span
// of the 32-node tile staged in LDS (lgkm) overlapping vmcnt gathers.
// Lists padded per node to a multiple of 8 with sentinel N (zero row).
//
// CSR build: fixed-capacity buckets (128 nodes/bucket, cap 3072 vs mean
// 2048, sigma ~45), TWO kernels. NOTE: in-kernel grid-barrier fusions
// measured 10x worse (R3: 506 MB refetch; R5: 135 us build) -- device-
// scope spin barriers serialize this chip; do not re-fuse.

#define HDIM 96
#define CIN 128
#define COUT 40
#define NLAYER 5
#define DTC 0.05f

#define BK_SHIFT 7
#define BK_SIZE 128
#define EPB 2048      // edges per block in bucket scatter
#define BCAP 3072     // fixed bucket capacity (mean 2048, >20 sigma margin)
#define BSTRIDE 4096  // csr region per bucket: BCAP + 1024 slack (mult-8 pad)

typedef float  vfloat2 __attribute__((ext_vector_type(2)));
typedef float  vfloat4 __attribute__((ext_vector_type(4)));
typedef short  vshort8 __attribute__((ext_vector_type(8)));

__device__ __forceinline__ unsigned bf16_rne(float f) {
    unsigned u = __float_as_uint(f);
    return (u + 0x7fffu + ((u >> 16) & 1u)) >> 16;
}

__device__ __forceinline__ unsigned pack_bf16_pair(float xf, float yf) {
    return bf16_rne(xf) | (bf16_rne(yf) << 16);
}

__device__ __forceinline__ unsigned pack_f16_pair(float a, float b) {
    unsigned ha = (unsigned)__half_as_ushort(__float2half_rn(a));
    unsigned hb = (unsigned)__half_as_ushort(__float2half_rn(b));
    return ha | (hb << 16);
}

__device__ __forceinline__ float f16_lo(unsigned u) {
    return __half2float(__ushort_as_half((unsigned short)(u & 0xffffu)));
}
__device__ __forceinline__ float f16_hi(unsigned u) {
    return __half2float(__ushort_as_half((unsigned short)(u >> 16)));
}

__device__ __forceinline__ unsigned pack_fp8_quad(float x0, float y0, float x1, float y1) {
    int lo = __builtin_amdgcn_cvt_pk_fp8_f32(x0, y0, 0, false);
    int full = __builtin_amdgcn_cvt_pk_fp8_f32(x1, y1, lo, true);
    return (unsigned)full;
}

// tanh via hw exp/rcp: 1 - 2/(e^{2x}+1). ~1e-7 err.
__device__ __forceinline__ float fast_tanh(float x) {
    float e = __expf(2.0f * x);
    return 1.0f - 2.0f * __builtin_amdgcn_rcpf(e + 1.0f);
}

// ---------------- Weight prep + cursor zero + sentinel zeroing ----------------

__global__ __launch_bounds__(256) void wprep_kernel(
    const float* __restrict__ Wx, const float* __restrict__ bx,
    const float* __restrict__ Wy, const float* __restrict__ by,
    unsigned short* __restrict__ WcT, float* __restrict__ bc,
    int* __restrict__ gcur, int NB,
    unsigned* __restrict__ F0, unsigned* __restrict__ F1, int N) {
    int t = blockIdx.x * blockDim.x + threadIdx.x;
    if (t < NB) gcur[t] = 0;
    if (t < 192 * 128) {
        int cc = t >> 7;
        int k = t & 127;
        int h = cc >> 1;
        float w = (cc & 1) ? Wy[k * HDIM + h] : Wx[k * HDIM + h];
        WcT[cc * 128 + k] = (unsigned short)bf16_rne(w);
    }
    if (t < 192) {
        int h = t >> 1;
        bc[t] = (t & 1) ? by[h] : bx[h];
    }
    if (blockIdx.x == 0 && threadIdx.x < 48) {
        // zero sentinel row N of each of the 3 planes, both F buffers
        int plane = threadIdx.x >> 4, d = threadIdx.x & 15;
        size_t o = ((size_t)plane * (N + 1) + N) * 16 + d;
        F0[o] = 0u;
        F1[o] = 0u;
    }
}

// ---------------- Bucket scatter (fixed-capacity, atomic-light) ----------------

__global__ __launch_bounds__(256) void bscatter_kernel(
    const int* __restrict__ src, const int* __restrict__ dst,
    int* __restrict__ gcur, unsigned* __restrict__ packed, int E, int NB) {
    __shared__ int h[512];
    __shared__ int cur[512];
    for (int i = threadIdx.x; i < NB; i += 256) h[i] = 0;
    __syncthreads();
    int base = blockIdx.x * EPB;
    int end = min(E, base + EPB);
    for (int e = base + threadIdx.x; e < end; e += 256)
        atomicAdd(&h[dst[e] >> BK_SHIFT], 1);
    __syncthreads();
    for (int i = threadIdx.x; i < NB; i += 256)
        cur[i] = h[i] ? atomicAdd(&gcur[i], h[i]) : 0;
    __syncthreads();
    for (int e = base + threadIdx.x; e < end; e += 256) {
        int d = dst[e];
        int b = d >> BK_SHIFT;
        int pos = atomicAdd(&cur[b], 1);
        if (pos < BCAP)  // never triggers at >20 sigma; guards OOB
            packed[(size_t)b * BCAP + pos] =
                (unsigned)src[e] | ((unsigned)(d & (BK_SIZE - 1)) << 17);
    }
}

// ---------------- Per-bucket CSR, per-node padding to multiple of 8 ----------------
// rowinfo[node] = { csr_begin (21b) | padded_count/4 << 21, bits(deg_inv) }
// csr entries are ushort node indices (sentinel = N). begin is a multiple
// of 8 -> every 8-index batch is one 16B-aligned uint4.

__global__ __launch_bounds__(256) void bcsr_kernel(
    const unsigned* __restrict__ packed, const int* __restrict__ gcur,
    uint2* __restrict__ rowinfo, unsigned short* __restrict__ csr, int N, int NB) {
    __shared__ int ldeg[BK_SIZE];
    __shared__ int sscan[BK_SIZE];
    __shared__ int lcur[BK_SIZE];
    int b = blockIdx.x;
    int t = threadIdx.x;
    int cnt = min(gcur[b], BCAP);
    const unsigned* pk = packed + (size_t)b * BCAP;
    int wbase = b * BSTRIDE;
    if (t < BK_SIZE) ldeg[t] = 0;
    __syncthreads();
    for (int e = t; e < cnt; e += 256)
        atomicAdd(&ldeg[(pk[e] >> 17) & (BK_SIZE - 1)], 1);
    __syncthreads();
    int deg = 0, pad = 0;
    if (t < BK_SIZE) {
        deg = ldeg[t];
        pad = (deg + 7) & ~7;
        sscan[t] = pad;
    }
    __syncthreads();
    for (int off = 1; off < BK_SIZE; off <<= 1) {
        int tv = (t < BK_SIZE && t >= off) ? sscan[t - off] : 0;
        __syncthreads();
        if (t < BK_SIZE) sscan[t] += tv;
        __syncthreads();
    }
    int gpos = 0;
    if (t < BK_SIZE) {
        gpos = wbase + sscan[t] - pad;  // exclusive padded offset
        lcur[t] = gpos;
        int node = b * BK_SIZE + t;
        if (node < N) {
            rowinfo[node] = make_uint2(
                (unsigned)gpos | ((unsigned)(pad >> 2) << 21),
                __float_as_uint(1.0f / fmaxf((float)deg, 1.0f)));
        }
    }
    __syncthreads();
    for (int e = t; e < cnt; e += 256) {
        unsigned p = pk[e];
        int l = (p >> 17) & (BK_SIZE - 1);
        int pos = atomicAdd(&lcur[l], 1);
        csr[pos] = (unsigned short)(p & 0x1FFFFu);
    }
    __syncthreads();
    if (t < BK_SIZE) {
        // fill pad slots with sentinel N (zero row)
        for (int p = lcur[t]; p < gpos + pad; p++) csr[p] = (unsigned short)N;
    }
}

// ---------------- Lift (MFMA): tanh(x @ [Wx|Wy] + b) ----------------

#define LW_STRIDE 136
#define TILE_STRIDE 200  // ushorts: 400 B rows, 16B-aligned

__global__ __launch_bounds__(256) void lift_mfma_kernel(
    const float* __restrict__ x, const unsigned short* __restrict__ WcT,
    const float* __restrict__ bc, unsigned* __restrict__ S,
    unsigned* __restrict__ F, int N) {
    __shared__ __align__(16) char smem[192 * LW_STRIDE * 2];  // 52224 B
    __shared__ float sBc[192];
    unsigned short* sW = (unsigned short*)smem;
    unsigned short* tile = (unsigned short*)smem;  // reused after barrier
    int t = threadIdx.x;

    {
        const unsigned* g = (const unsigned*)WcT;  // 192*64 uints
        unsigned* s = (unsigned*)sW;
        for (int i = t; i < 192 * 64; i += 256) {
            int cc = i >> 6;
            int kp = i & 63;
            s[cc * (LW_STRIDE / 2) + kp] = g[i];
        }
    }
    if (t < 192) sBc[t] = bc[t];
    __syncthreads();

    int wv = t >> 6;
    int lane = t & 63;
    int quad = lane >> 4;
    int m = lane & 15;
    int mbase = blockIdx.x * 64 + wv * 16;

    int anode = mbase + m;
    if (anode >= N) anode = N - 1;  // clamp; stores guarded
    const float* xrow = x + (size_t)anode * CIN;

    vfloat4 acc[12];
#pragma unroll
    for (int i = 0; i < 12; i++) acc[i] = (vfloat4){0.f, 0.f, 0.f, 0.f};

#pragma unroll
    for (int kt = 0; kt < 4; kt++) {
        int k0 = kt * 32 + quad * 8;
        float4 xa = *(const float4*)(xrow + k0);
        float4 xb = *(const float4*)(xrow + k0 + 4);
        uint4 ua;
        ua.x = pack_bf16_pair(xa.x, xa.y);
        ua.y = pack_bf16_pair(xa.z, xa.w);
        ua.z = pack_bf16_pair(xb.x, xb.y);
        ua.w = pack_bf16_pair(xb.z, xb.w);
        vshort8 a = *(vshort8*)&ua;
#pragma unroll
        for (int nt = 0; nt < 12; nt++) {
            vshort8 b = *(const vshort8*)&sW[(nt * 16 + m) * LW_STRIDE + k0];
            acc[nt] = __builtin_amdgcn_mfma_f32_16x16x32_bf16(a, b, acc[nt], 0, 0, 0);
        }
    }

    // ---- epilogue phase 1: tanh + fp16 into LDS tile ----
    __syncthreads();  // all waves done reading sW
#pragma unroll
    for (int nt = 0; nt < 12; nt++) {
        int ccb = nt * 16 + m;
        float bco = sBc[ccb];
#pragma unroll
        for (int r = 0; r < 4; r++) {
            int nl = wv * 16 + quad * 4 + r;  // local node 0..63
            float v = fast_tanh(acc[nt][r] + bco);
            tile[nl * TILE_STRIDE + ccb] = __half_as_ushort(__float2half_rn(v));
        }
    }
    __syncthreads();

    // ---- epilogue phase 2: coalesced S (uint4) + plane-F (uint2) stores ----
    int nbase = blockIdx.x * 64;
#pragma unroll
    for (int i = 0; i < 6; i++) {
        int idx = i * 256 + t;       // 0..1535
        int nl = idx / 24;           // local node (24 uint4 per 96-dword row)
        int pos = idx - nl * 24;
        int node = nbase + nl;
        uint4 u = *(const uint4*)&tile[nl * TILE_STRIDE + pos * 8];
        if (node < N) {
            *(uint4*)(S + (size_t)node * 96 + pos * 4) = u;
            float f0 = f16_lo(u.x), f1 = f16_hi(u.x);
            float f2 = f16_lo(u.y), f3 = f16_hi(u.y);
            float f4 = f16_lo(u.z), f5 = f16_hi(u.z);
            float f6 = f16_lo(u.w), f7 = f16_hi(u.w);
            uint2 fq = make_uint2(pack_fp8_quad(f0, f1, f2, f3),
                                  pack_fp8_quad(f4, f5, f6, f7));
            // global F dword pair (2pos, 2pos+1) -> plane = pos/8, slot = 2pos mod 16
            int plane = pos >> 3;
            int slot = (2 * pos) & 15;
            *(uint2*)(F + ((size_t)plane * (N + 1) + node) * 16 + slot) = fq;
        }
    }
}

// ---------------- Layer pass: mean agg + LV Euler update (one plane/tile) ----------------
// XCD-pinned task map: xcd = bid & 7 (hw round-robin); task = xcd*T + bid/8
// over a plane-major task list (plane = task/nblk, tile = task%nblk). Each
// XCD thus works through a contiguous plane-major slice -> each plane is
// resident in only 3-4 XCD L2s. Tile = 32 nodes (4 waves x 8 groups);
// group owns a node, li = lane&7 owns F dwords {2li, 2li+1}. The tile's
// csr span is staged in LDS (lgkm reads overlap vmcnt gathers).

#define SPAN_CAP 4096  // ushorts (8 KB LDS); fallback to global if exceeded

__global__ __launch_bounds__(256) void layer_kernel(
    const unsigned* __restrict__ F, unsigned* __restrict__ S,
    unsigned* __restrict__ Fn,
    const uint2* __restrict__ rowinfo, const unsigned short* __restrict__ csr,
    const float* __restrict__ alpha, const float* __restrict__ beta,
    const float* __restrict__ gamma, const float* __restrict__ delta,
    int N, int nblk, int T) {
    __shared__ __align__(16) unsigned short sidx[SPAN_CAP];
    int bid = blockIdx.x;
    int task = (bid & 7) * T + (bid >> 3);   // XCD-pinned plane-major slice
    if (task >= 3 * nblk) return;
    int plane = (task >= nblk) + (task >= 2 * nblk);
    int tile = task - plane * nblk;
    unsigned pstride = (unsigned)(N + 1) * 16u;
    const unsigned* Fp = F + (size_t)plane * pstride;

    int t = threadIdx.x;
    int wave = t >> 6;
    int lane = t & 63;
    int li = lane & 7;
    unsigned tli = (unsigned)(2 * li);

    // ---- stage the tile's csr span in LDS ----
    int n0 = tile * 32;
    int nlast = min(n0 + 31, N - 1);
    unsigned ri0x = rowinfo[n0].x;
    unsigned riLx = rowinfo[nlast].x;
    unsigned beg0 = ri0x & 0x1FFFFFu;
    unsigned endL = (riLx & 0x1FFFFFu) + ((riLx >> 21) << 2);
    int span = (int)(endL - beg0);     // multiple of 8
    bool use_lds = (span <= SPAN_CAP);
    if (use_lds) {
        const uint4* gs = (const uint4*)(csr + beg0);
        uint4* ld = (uint4*)sidx;
        for (int i = t; i < (span >> 3); i += 256) ld[i] = gs[i];
    }

    int node = n0 + wave * 8 + (lane >> 3);
    bool nvalid = node < N;
    int nclamp = nvalid ? node : N - 1;
    uint2 ri = rowinfo[nclamp];
    unsigned beg = ri.x & 0x1FFFFFu;
    int cnt = nvalid ? (int)((ri.x >> 21) << 2) : 0;  // padded, multiple of 8
    float dinv = __uint_as_float(ri.y);

    __syncthreads();

    // a_k = (sum X, sum Y) of channel h0+k
    vfloat2 a0 = {0.f, 0.f}, a1 = {0.f, 0.f}, a2 = {0.f, 0.f}, a3 = {0.f, 0.f};

#define UNP(u)                                                              \
    do {                                                                    \
        a0 += __builtin_amdgcn_cvt_pk_f32_fp8((int)(u).x, false);           \
        a1 += __builtin_amdgcn_cvt_pk_f32_fp8((int)(u).x, true);            \
        a2 += __builtin_amdgcn_cvt_pk_f32_fp8((int)(u).y, false);           \
        a3 += __builtin_amdgcn_cvt_pk_f32_fp8((int)(u).y, true);            \
    } while (0)

#define GBODY(WEXPR)                                                        \
    _Pragma("unroll 2")                                                     \
    for (int j = 0; j < cnt; j += 8) {                                      \
        uint4 w = WEXPR;                                                    \
        unsigned o0 = ((w.x & 0xffffu) << 4) + tli;                         \
        unsigned o1 = ((w.x >> 16) << 4) + tli;                             \
        unsigned o2 = ((w.y & 0xffffu) << 4) + tli;                         \
        unsigned o3 = ((w.y >> 16) << 4) + tli;                             \
        unsigned o4 = ((w.z & 0xffffu) << 4) + tli;                         \
        unsigned o5 = ((w.z >> 16) << 4) + tli;                             \
        unsigned o6 = ((w.w & 0xffffu) << 4) + tli;                         \
        unsigned o7 = ((w.w >> 16) << 4) + tli;                             \
        uint2 u0 = *(const uint2*)(Fp + o0);                                \
        uint2 u1 = *(const uint2*)(Fp + o1);                                \
        uint2 u2 = *(const uint2*)(Fp + o2);                                \
        uint2 u3 = *(const uint2*)(Fp + o3);                                \
        uint2 u4 = *(const uint2*)(Fp + o4);                                \
        uint2 u5 = *(const uint2*)(Fp + o5);                                \
        uint2 u6 = *(const uint2*)(Fp + o6);                                \
        uint2 u7 = *(const uint2*)(Fp + o7);                                \
        UNP(u0); UNP(u1); UNP(u2); UNP(u3);                                 \
        UNP(u4); UNP(u5); UNP(u6); UNP(u7);                                 \
    }

    if (use_lds) {
        unsigned lbeg = beg - beg0;
        GBODY((*(const uint4*)(sidx + lbeg + (unsigned)j)))
    } else {
        GBODY((*(const uint4*)(csr + beg + (unsigned)j)))
    }
#undef GBODY
#undef UNP

    if (!nvalid) return;

    int h0 = plane * 32 + 4 * li;
    float4 av = *(const float4*)(alpha + h0);
    float4 bv = *(const float4*)(beta + h0);
    float4 gv = *(const float4*)(gamma + h0);
    float4 dv = *(const float4*)(delta + h0);
    unsigned* srow = S + (size_t)node * 96 + h0;
    uint4 su = *(const uint4*)srow;

    float x0 = f16_lo(su.x), y0 = f16_hi(su.x);
    float x1 = f16_lo(su.y), y1 = f16_hi(su.y);
    float x2 = f16_lo(su.z), y2 = f16_hi(su.z);
    float x3 = f16_lo(su.w), y3 = f16_hi(su.w);

    float ox0 = x0 + DTC * x0 * (av.x - bv.x * (a0.y * dinv));
    float oy0 = y0 + DTC * y0 * (-gv.x + dv.x * (a0.x * dinv));
    float ox1 = x1 + DTC * x1 * (av.y - bv.y * (a1.y * dinv));
    float oy1 = y1 + DTC * y1 * (-gv.y + dv.y * (a1.x * dinv));
    float ox2 = x2 + DTC * x2 * (av.z - bv.z * (a2.y * dinv));
    float oy2 = y2 + DTC * y2 * (-gv.z + dv.z * (a2.x * dinv));
    float ox3 = x3 + DTC * x3 * (av.w - bv.w * (a3.y * dinv));
    float oy3 = y3 + DTC * y3 * (-gv.w + dv.w * (a3.x * dinv));

    uint4 so;
    so.x = pack_f16_pair(ox0, oy0);
    so.y = pack_f16_pair(ox1, oy1);
    so.z = pack_f16_pair(ox2, oy2);
    so.w = pack_f16_pair(ox3, oy3);
    *(uint4*)srow = so;

    if (Fn) {
        uint2 fo;
        fo.x = pack_fp8_quad(ox0, oy0, ox1, oy1);
        fo.y = pack_fp8_quad(ox2, oy2, ox3, oy3);
        *(uint2*)(Fn + (size_t)plane * pstride + (unsigned)node * 16u + tli) = fo;
    }
}

// ---------------- Readout: out = [X,Y] @ Wr + br via f16 MFMA ----------------

#define WG_STRIDE 200

__global__ __launch_bounds__(256) void readout_mfma_kernel(
    const unsigned short* __restrict__ sh, const float* __restrict__ Wr,
    const float* __restrict__ br, float* __restrict__ out, int N) {
    __shared__ unsigned short sW[48 * WG_STRIDE];
    __shared__ float sB[48];
    int t = threadIdx.x;

    for (int i = t; i < 48 * 192; i += 256) {
        int n = i / 192;
        int kk = i - n * 192;
        int h = kk >> 1;
        float w = 0.f;
        if (n < COUT) w = (kk & 1) ? Wr[(HDIM + h) * COUT + n] : Wr[h * COUT + n];
        sW[n * WG_STRIDE + kk] = __half_as_ushort(__float2half_rn(w));
    }
    if (t < 48) sB[t] = (t < COUT) ? br[t] : 0.f;
    __syncthreads();

    int wv = t >> 6;
    int lane = t & 63;
    int quad = lane >> 4;
    int m = lane & 15;
    int mbase = blockIdx.x * 64 + wv * 16;

    int anode = mbase + m;
    if (anode >= N) anode = N - 1;
    const unsigned short* arow = sh + (size_t)anode * 192;

    vfloat4 acc0 = {0.f, 0.f, 0.f, 0.f};
    vfloat4 acc1 = {0.f, 0.f, 0.f, 0.f};
    vfloat4 acc2 = {0.f, 0.f, 0.f, 0.f};

#pragma unroll
    for (int kt = 0; kt < 6; kt++) {
        int k0 = kt * 32 + quad * 8;
        vshort8 a = *(const vshort8*)(arow + k0);
        vshort8 b0 = *(const vshort8*)&sW[(0 * 16 + m) * WG_STRIDE + k0];
        vshort8 b1 = *(const vshort8*)&sW[(1 * 16 + m) * WG_STRIDE + k0];
        vshort8 b2 = *(const vshort8*)&sW[(2 * 16 + m) * WG_STRIDE + k0];
        acc0 = __builtin_amdgcn_mfma_f32_16x16x32_f16(a, b0, acc0, 0, 0, 0);
        acc1 = __builtin_amdgcn_mfma_f32_16x16x32_f16(a, b1, acc1, 0, 0, 0);
        acc2 = __builtin_amdgcn_mfma_f32_16x16x32_f16(a, b2, acc2, 0, 0, 0);
    }

    float bo0 = sB[m];
    float bo1 = sB[16 + m];
    float bo2 = (m < 8) ? sB[32 + m] : 0.f;
#pragma unroll
    for (int r = 0; r < 4; r++) {
        int node = mbase + quad * 4 + r;
        if (node < N) {
            float* orow = out + (size_t)node * COUT;
            orow[m] = acc0[r] + bo0;
            orow[16 + m] = acc1[r] + bo1;
            if (m < 8) orow[32 + m] = acc2[r] + bo2;
        }
    }
}

// ---------------- launch ----------------

extern "C" void kernel_launch(void* const* d_in, const int* in_sizes, int n_in,
                              void* d_out, int out_size, void* d_ws, size_t ws_size,
                              hipStream_t stream) {
    const float* x     = (const float*)d_in[0];
    const int*   ei    = (const int*)d_in[1];
    const float* Wx    = (const float*)d_in[2];
    const float* bx    = (const float*)d_in[3];
    const float* Wy    = (const float*)d_in[4];
    const float* by    = (const float*)d_in[5];
    const float* alpha = (const float*)d_in[6];
    const float* beta  = (const float*)d_in[7];
    const float* gamma = (const float*)d_in[8];
    const float* delta = (const float*)d_in[9];
    const float* Wr    = (const float*)d_in[10];
    const float* br    = (const float*)d_in[11];

    const int N = in_sizes[0] / CIN;
    const int E = in_sizes[1] / 2;
    const int NB = (N + BK_SIZE - 1) >> BK_SHIFT;     // 391 for N=50000 (<=512)
    const int nchunk = (E + EPB - 1) / EPB;           // 391 for E=800000
    const int nblk = (N + 31) / 32;                   // 1563 32-node tiles
    const int T = (3 * nblk + 7) / 8;                 // tasks per XCD slot
    const int lgrid = 8 * T;                          // layer grid (<=7 idle)

    char* ws = (char*)d_ws;
    size_t off = 0;
    auto alloc = [&](size_t bytes) -> void* {
        off = (off + 255) & ~(size_t)255;
        void* p = ws + off;
        off += bytes;
        return p;
    };
    int* gcur          = (int*)alloc((size_t)NB * sizeof(int));
    unsigned* pckd     = (unsigned*)alloc((size_t)NB * BCAP * sizeof(unsigned));
    uint2* rowinfo     = (uint2*)alloc((size_t)N * sizeof(uint2));
    unsigned short* csr = (unsigned short*)alloc(((size_t)NB * BSTRIDE + 64) * sizeof(unsigned short));
    unsigned* Sa   = (unsigned*)alloc((size_t)N * 96 * sizeof(unsigned));        // fp16 state (in-place)
    unsigned* Fa   = (unsigned*)alloc((size_t)(N + 1) * 48 * sizeof(unsigned));  // 3 fp8 planes
    unsigned* Fb   = (unsigned*)alloc((size_t)(N + 1) * 48 * sizeof(unsigned));
    unsigned short* WcT = (unsigned short*)alloc((size_t)192 * 128 * sizeof(unsigned short));
    float* bc      = (float*)alloc((size_t)192 * sizeof(float));
    (void)ws_size;

    const int* e_src = ei;
    const int* e_dst = ei + E;

    // wprep first: zeroes bucket cursors + sentinel F rows, builds WcT/bc
    wprep_kernel<<<(192 * 128 + 255) / 256, 256, 0, stream>>>(
        Wx, bx, Wy, by, WcT, bc, gcur, NB, Fa, Fb, N);

    bscatter_kernel<<<nchunk, 256, 0, stream>>>(e_src, e_dst, gcur, pckd, E, NB);
    bcsr_kernel<<<NB, 256, 0, stream>>>(pckd, gcur, rowinfo, csr, N, NB);

    lift_mfma_kernel<<<(N + 63) / 64, 256, 0, stream>>>(x, WcT, bc, Sa, Fa, N);

    const unsigned* Fc = Fa;
    unsigned* Fnx = Fb;
    for (int l = 0; l < NLAYER; l++) {
        bool last = (l == NLAYER - 1);
        layer_kernel<<<lgrid, 256, 0, stream>>>(
            Fc, Sa, last ? (unsigned*)nullptr : Fnx,
            rowinfo, csr,
            alpha + l * HDIM, beta + l * HDIM, gamma + l * HDIM, delta + l * HDIM,
            N, nblk, T);
        const unsigned* tf = Fc; Fc = Fnx; Fnx = (unsigned*)tf;
    }

    readout_mfma_kernel<<<(N + 63) / 64, 256, 0, stream>>>(
        (const unsigned short*)Sa, Wr, br, (float*)d_out, N);
}